// Round 4
// baseline (108.109 us; speedup 1.0000x reference)
//
#include <hip/hip_runtime.h>
#include <hip/hip_bf16.h>

typedef __attribute__((ext_vector_type(8))) __bf16 bf16x8;
typedef __attribute__((ext_vector_type(4))) float f32x4;

#define NROWS 16384
#define DIM   2048
#define NH1   512
#define NH2   32
#define MMEM  2048
#define BK    64
#define NT2   (DIM / BK)   // 32 K-steps

// workspace byte offsets
#define W1O ((size_t)0)            // W1 bf16:  512*2048*2   = 2097152
#define W2O ((size_t)2097152)      // W2 bf16:  32*512*2     = 32768
#define AMO ((size_t)2129920)      // a_mem:    2048*32*2    = 131072
#define NMO ((size_t)2260992)      // n_mem:    2048*32*2    = 131072
#define HO  ((size_t)2392064)      // h bf16:   16384*512*2  = 16777216

__device__ __forceinline__ f32x4 mfma16(bf16x8 a, bf16x8 b, f32x4 c) {
    return __builtin_amdgcn_mfma_f32_16x16x32_bf16(a, b, c, 0, 0, 0);
}

__device__ __forceinline__ void gload_lds16(const void* g, void* l) {
    __builtin_amdgcn_global_load_lds(
        (const __attribute__((address_space(1))) void*)g,
        (__attribute__((address_space(3))) void*)l, 16, 0, 0);
}

__device__ __forceinline__ bf16x8 cvt8(f32x4 a, f32x4 b) {
    bf16x8 o;
    o[0] = (__bf16)a[0]; o[1] = (__bf16)a[1]; o[2] = (__bf16)a[2]; o[3] = (__bf16)a[3];
    o[4] = (__bf16)b[0]; o[5] = (__bf16)b[1]; o[6] = (__bf16)b[2]; o[7] = (__bf16)b[3];
    return o;
}

// ---------------- merged f32 -> bf16 conversion for W1, W2, am, nm ----------------
struct bf4 { __bf16 a, b, c, d; };

__global__ void cvt_all_kernel(const float* __restrict__ w1f, __bf16* __restrict__ w1b,
                               const float* __restrict__ w2f, __bf16* __restrict__ w2b,
                               const float* __restrict__ amf, __bf16* __restrict__ amb,
                               const float* __restrict__ nmf, __bf16* __restrict__ nmb) {
    const int g = blockIdx.x * blockDim.x + threadIdx.x;
    const int T = gridDim.x * blockDim.x;
    for (int i = g; i < (NH1 * DIM) / 4; i += T) {
        const float4 v = *reinterpret_cast<const float4*>(w1f + i * 4);
        *reinterpret_cast<bf4*>(w1b + i * 4) = { (__bf16)v.x, (__bf16)v.y, (__bf16)v.z, (__bf16)v.w };
    }
    for (int i = g; i < (NH2 * NH1) / 4; i += T) {
        const float4 v = *reinterpret_cast<const float4*>(w2f + i * 4);
        *reinterpret_cast<bf4*>(w2b + i * 4) = { (__bf16)v.x, (__bf16)v.y, (__bf16)v.z, (__bf16)v.w };
    }
    for (int i = g; i < (MMEM * NH2) / 4; i += T) {
        const float4 v = *reinterpret_cast<const float4*>(amf + i * 4);
        *reinterpret_cast<bf4*>(amb + i * 4) = { (__bf16)v.x, (__bf16)v.y, (__bf16)v.z, (__bf16)v.w };
    }
    for (int i = g; i < (MMEM * NH2) / 4; i += T) {
        const float4 v = *reinterpret_cast<const float4*>(nmf + i * 4);
        *reinterpret_cast<bf4*>(nmb + i * 4) = { (__bf16)v.x, (__bf16)v.y, (__bf16)v.z, (__bf16)v.w };
    }
}

// ---------------- GEMM1: h = relu(x @ W1^T + b1) ----------------
// 128x128 tile, BK=64, 4 waves (2x2, wave-tile 64x64). Double-buffered LDS with
// XOR swizzle byte^=((row&7)<<4). A: f32 reg-stage + cvt + swizzled ds_write.
// B: global_load_lds with pre-swizzled global source (linear LDS dest).
// One counted-vmcnt barrier per K-step.
__global__ __launch_bounds__(256, 2) void gemm1_kernel(
    const float*  __restrict__ Xf,  // [NROWS][DIM] f32
    const __bf16* __restrict__ W1,  // [NH1][DIM] bf16
    const float*  __restrict__ b1,  // [NH1]
    __bf16* __restrict__ Hout)      // [NROWS][NH1]
{
    // each tile: [128 rows][64 k] bf16 = 16 KB
    __shared__ __bf16 bufA[2][128 * BK];
    __shared__ __bf16 bufB[2][128 * BK];
    const int tid  = threadIdx.x;
    const int lane = tid & 63;
    const int wave = tid >> 6;
    // XCD swizzle: nwg=512 = 8*64. XCD c gets orig c*64..c*64+63 (16 row-panels x 4 cols)
    const int b = blockIdx.x;
    const int orig = (b & 7) * 64 + (b >> 3);
    const int bn = orig & 3;    // 4 col tiles of 128
    const int bm = orig >> 2;   // 128 row tiles of 128
    const size_t brow = (size_t)bm * 128;
    const int bcol = bn * 128;
    const int wr = wave >> 1, wc = wave & 1;

    f32x4 acc[4][4];
#pragma unroll
    for (int m = 0; m < 4; ++m)
#pragma unroll
        for (int n = 0; n < 4; ++n) acc[m][n] = (f32x4){0.f, 0.f, 0.f, 0.f};

    // ---- A staging geometry: thread t covers row t>>1, 64B-half t&1 (slots h*4..h*4+3)
    const int aRow  = tid >> 1;
    const int aHalf = tid & 1;
    const float* aSrc = Xf + (brow + aRow) * (size_t)DIM + aHalf * 32;  // + k0 per step
    int aOffB[4];  // LDS byte offsets (swizzled) for the 4 slots
#pragma unroll
    for (int j = 0; j < 4; ++j)
        aOffB[j] = aRow * 128 + (((aHalf * 4 + j) ^ (aRow & 7)) << 4);

    // ---- B staging geometry: issue q in 0..3; lane covers row q*32 + wave*8 + (l>>3),
    // global chunk (l&7)^(l>>3), LDS linear byte q*4096 + wave*1024 + lane*16
    const int bRowL  = wave * 8 + (lane >> 3);
    const int bChunk = (lane & 7) ^ (lane >> 3);
    const char* bSrcBase = (const char*)W1 + ((size_t)(bcol + bRowL) * DIM) * 2 + bChunk * 16;
    const int bLdsOff = wave * 1024 + lane * 16;  // + q*4096

    // ---- fragment read geometry
    const int l15 = lane & 15;
    const int kc  = lane >> 4;
    const int l7  = lane & 7;
    const int rABase = wr * 64 + l15;
    const int rBBase = wc * 64 + l15;

    // ================= prologue: stage tile 0, prefetch A(1) =================
    f32x4 pa[8];
    {
        f32x4 ta[8];
#pragma unroll
        for (int j = 0; j < 4; ++j) {
            ta[2 * j]     = *(const f32x4*)(aSrc + j * 8);
            ta[2 * j + 1] = *(const f32x4*)(aSrc + j * 8 + 4);
        }
#pragma unroll
        for (int q = 0; q < 4; ++q)
            gload_lds16(bSrcBase + (size_t)q * 32 * DIM * 2,
                        (char*)bufB[0] + q * 4096 + bLdsOff);
        __builtin_amdgcn_sched_barrier(0);
#pragma unroll
        for (int j = 0; j < 4; ++j)
            *(bf16x8*)((char*)bufA[0] + aOffB[j]) = cvt8(ta[2 * j], ta[2 * j + 1]);
        __builtin_amdgcn_sched_barrier(0);
#pragma unroll
        for (int j = 0; j < 4; ++j) {
            pa[2 * j]     = *(const f32x4*)(aSrc + BK + j * 8);
            pa[2 * j + 1] = *(const f32x4*)(aSrc + BK + j * 8 + 4);
        }
        __builtin_amdgcn_sched_barrier(0);
    }
    asm volatile("s_waitcnt vmcnt(8) lgkmcnt(0)" ::: "memory");
    __builtin_amdgcn_s_barrier();

    // ================= main loop =================
    for (int t = 0; t < NT2 - 1; ++t) {
        const int cur = t & 1;
        const __bf16* Acur = bufA[cur];
        const __bf16* Bcur = bufB[cur];
        char* Anxt = (char*)bufA[cur ^ 1];
        char* Bnxt = (char*)bufB[cur ^ 1];

        // 1) issue B(t+1) gloads (4)
        {
            const char* bs = bSrcBase + (size_t)(t + 1) * BK * 2;
#pragma unroll
            for (int q = 0; q < 4; ++q)
                gload_lds16(bs + (size_t)q * 32 * DIM * 2, Bnxt + q * 4096 + bLdsOff);
        }
        __builtin_amdgcn_sched_barrier(0);

        // 2) write A(t+1) from pa (auto-waits pa; B's 4 gloads stay outstanding)
#pragma unroll
        for (int j = 0; j < 4; ++j)
            *(bf16x8*)(Anxt + aOffB[j]) = cvt8(pa[2 * j], pa[2 * j + 1]);
        __builtin_amdgcn_sched_barrier(0);

        // 3) issue A(t+2) f32 prefetch (8) — stays in flight across the barrier
        f32x4 qa[8];
        {
            const int tq = (t + 2 < NT2) ? (t + 2) : 0;
            const float* qs = aSrc + (size_t)tq * BK;
#pragma unroll
            for (int j = 0; j < 4; ++j) {
                qa[2 * j]     = *(const f32x4*)(qs + j * 8);
                qa[2 * j + 1] = *(const f32x4*)(qs + j * 8 + 4);
            }
        }
        __builtin_amdgcn_sched_barrier(0);

        // 4) compute tile t: 2 kk sub-steps, 8 swizzled ds_read_b128 + 16 MFMA each
#pragma unroll
        for (int kk = 0; kk < 2; ++kk) {
            const int c = kk * 4 + kc;
            const int slot = (c ^ l7) << 4;
            bf16x8 av[4], bv[4];
#pragma unroll
            for (int m = 0; m < 4; ++m)
                av[m] = *(const bf16x8*)((const char*)Acur + (rABase + m * 16) * 128 + slot);
#pragma unroll
            for (int n = 0; n < 4; ++n)
                bv[n] = *(const bf16x8*)((const char*)Bcur + (rBBase + n * 16) * 128 + slot);
#pragma unroll
            for (int m = 0; m < 4; ++m)
#pragma unroll
                for (int n = 0; n < 4; ++n)
                    acc[m][n] = mfma16(av[m], bv[n], acc[m][n]);
        }

        // 5) B(t+1) drained (oldest 4); qa (8) stay in flight. ds ops visible.
        asm volatile("s_waitcnt vmcnt(8) lgkmcnt(0)" ::: "memory");
        __builtin_amdgcn_s_barrier();

#pragma unroll
        for (int j = 0; j < 8; ++j) pa[j] = qa[j];
    }

    // ================= final tile =================
    {
        const int cur = (NT2 - 1) & 1;
        const __bf16* Acur = bufA[cur];
        const __bf16* Bcur = bufB[cur];
#pragma unroll
        for (int kk = 0; kk < 2; ++kk) {
            const int c = kk * 4 + kc;
            const int slot = (c ^ l7) << 4;
            bf16x8 av[4], bv[4];
#pragma unroll
            for (int m = 0; m < 4; ++m)
                av[m] = *(const bf16x8*)((const char*)Acur + (rABase + m * 16) * 128 + slot);
#pragma unroll
            for (int n = 0; n < 4; ++n)
                bv[n] = *(const bf16x8*)((const char*)Bcur + (rBBase + n * 16) * 128 + slot);
#pragma unroll
            for (int m = 0; m < 4; ++m)
#pragma unroll
                for (int n = 0; n < 4; ++n)
                    acc[m][n] = mfma16(av[m], bv[n], acc[m][n]);
        }
    }

    // epilogue: bias + relu + bf16 store. D layout: col=lane&15, row=(lane>>4)*4+reg
#pragma unroll
    for (int n = 0; n < 4; ++n) {
        const int gcol = bcol + wc * 64 + n * 16 + l15;
        const float bias = b1[gcol];
#pragma unroll
        for (int m = 0; m < 4; ++m) {
            const size_t grow0 = brow + wr * 64 + m * 16 + kc * 4;
#pragma unroll
            for (int r = 0; r < 4; ++r) {
                float v = acc[m][n][r] + bias;
                v = v > 0.f ? v : 0.f;
                Hout[(grow0 + r) * NH1 + gcol] = (__bf16)v;
            }
        }
    }
}

// ---------------- Tail: feat = h@W2^T + b2; scores; sigmoid ----------------
__global__ __launch_bounds__(512) void tail_kernel(
    const __bf16* __restrict__ Hin,  // [NROWS][NH1]
    const __bf16* __restrict__ W2b,  // [NH2][NH1]
    const float*  __restrict__ b2,   // [NH2]
    const __bf16* __restrict__ Am,   // [MMEM][NH2]
    const __bf16* __restrict__ Nm,   // [MMEM][NH2]
    float* __restrict__ out)         // [NROWS]
{
    __shared__ __bf16 featLds[64 * 32];
    __shared__ float aMaxLds[2][64];
    __shared__ float nMaxLds[2][64];
    const int tid  = threadIdx.x;
    const int lane = tid & 63;
    const int wave = tid >> 6;          // 0..7
    const int rowBase = blockIdx.x * 64;
    const int l15 = lane & 15;
    const int kc  = lane >> 4;
    const int rgrp  = (wave & 3) * 16;
    const int jHalf = wave >> 2;

    if (wave < 4) {
        f32x4 acc0 = {0.f,0.f,0.f,0.f}, acc1 = {0.f,0.f,0.f,0.f};
        const size_t hrow = (size_t)(rowBase + rgrp + l15) * NH1;
#pragma unroll
        for (int kk = 0; kk < 16; ++kk) {
            bf16x8 a  = *(const bf16x8*)(Hin + hrow + kk * 32 + kc * 8);
            bf16x8 w0 = *(const bf16x8*)(W2b + (size_t)l15 * NH1 + kk * 32 + kc * 8);
            bf16x8 w1 = *(const bf16x8*)(W2b + (size_t)(16 + l15) * NH1 + kk * 32 + kc * 8);
            acc0 = mfma16(a, w0, acc0);
            acc1 = mfma16(a, w1, acc1);
        }
        const float bias0 = b2[l15], bias1 = b2[16 + l15];
#pragma unroll
        for (int r = 0; r < 4; ++r) {
            const int lr = rgrp + kc * 4 + r;
            featLds[lr * 32 + l15]      = (__bf16)(acc0[r] + bias0);
            featLds[lr * 32 + 16 + l15] = (__bf16)(acc1[r] + bias1);
        }
    }
    __syncthreads();

    const bf16x8 af = *(const bf16x8*)&featLds[(rgrp + l15) * 32 + kc * 8];

    float rmaxA[4], rmaxN[4];
#pragma unroll
    for (int r = 0; r < 4; ++r) { rmaxA[r] = -1e30f; rmaxN[r] = -1e30f; }
    const f32x4 zero = {0.f,0.f,0.f,0.f};
    const int jBase = jHalf * (MMEM / 2);
#pragma unroll 2
    for (int jt = 0; jt < (MMEM / 2) / 16; jt += 4) {
        bf16x8 ba[4], bb[4];
#pragma unroll
        for (int u = 0; u < 4; ++u) {
            const size_t off = (size_t)(jBase + (jt + u) * 16 + l15) * NH2 + kc * 8;
            ba[u] = *(const bf16x8*)(Am + off);
            bb[u] = *(const bf16x8*)(Nm + off);
        }
#pragma unroll
        for (int u = 0; u < 4; ++u) {
            f32x4 sa = mfma16(af, ba[u], zero);
            f32x4 sn = mfma16(af, bb[u], zero);
#pragma unroll
            for (int r = 0; r < 4; ++r) {
                rmaxA[r] = fmaxf(rmaxA[r], sa[r]);
                rmaxN[r] = fmaxf(rmaxN[r], sn[r]);
            }
        }
    }
#pragma unroll
    for (int off = 1; off < 16; off <<= 1) {
#pragma unroll
        for (int r = 0; r < 4; ++r) {
            rmaxA[r] = fmaxf(rmaxA[r], __shfl_xor(rmaxA[r], off, 64));
            rmaxN[r] = fmaxf(rmaxN[r], __shfl_xor(rmaxN[r], off, 64));
        }
    }
    if (l15 == 0) {
#pragma unroll
        for (int r = 0; r < 4; ++r) {
            const int row = rgrp + kc * 4 + r;
            aMaxLds[jHalf][row] = rmaxA[r];
            nMaxLds[jHalf][row] = rmaxN[r];
        }
    }
    __syncthreads();
    if (tid < 64) {
        const float ma = fmaxf(aMaxLds[0][tid], aMaxLds[1][tid]);
        const float mn = fmaxf(nMaxLds[0][tid], nMaxLds[1][tid]);
        const float d = (ma - mn) * (1.0f / 32.0f);
        out[rowBase + tid] = 1.0f / (1.0f + __expf(-d));
    }
}

extern "C" void kernel_launch(void* const* d_in, const int* in_sizes, int n_in,
                              void* d_out, int out_size, void* d_ws, size_t ws_size,
                              hipStream_t stream) {
    (void)in_sizes; (void)n_in; (void)out_size; (void)ws_size;
    const float* x  = (const float*)d_in[0];
    const float* W1 = (const float*)d_in[1];
    const float* b1 = (const float*)d_in[2];
    const float* W2 = (const float*)d_in[3];
    const float* b2 = (const float*)d_in[4];
    const float* am = (const float*)d_in[5];
    const float* nm = (const float*)d_in[6];
    float* out = (float*)d_out;
    char* ws = (char*)d_ws;
    __bf16* w1b = (__bf16*)(ws + W1O);
    __bf16* w2b = (__bf16*)(ws + W2O);
    __bf16* amb = (__bf16*)(ws + AMO);
    __bf16* nmb = (__bf16*)(ws + NMO);
    __bf16* hb  = (__bf16*)(ws + HO);

    cvt_all_kernel<<<dim3(512), dim3(256), 0, stream>>>(W1, w1b, W2, w2b, am, amb, nm, nmb);
    gemm1_kernel<<<dim3((NROWS / 128) * (NH1 / 128)), dim3(256), 0, stream>>>(x, w1b, b1, hb);
    tail_kernel<<<dim3(NROWS / 64), dim3(512), 0, stream>>>(hb, w2b, b2, amb, nmb, out);
}

// Round 5
// 81.670 us; speedup vs baseline: 1.3237x; 1.3237x over previous
//
#include <hip/hip_runtime.h>
#include <hip/hip_bf16.h>

typedef __attribute__((ext_vector_type(8))) __bf16 bf16x8;
typedef __attribute__((ext_vector_type(4))) float f32x4;

#define NROWS 16384
#define DIM   2048
#define NH1   512
#define NH2   32
#define MMEM  2048
#define BK    32
#define NT    (DIM / BK)   // 64 K-steps

// workspace byte offsets
#define W1O ((size_t)0)            // W1 bf16:  512*2048*2   = 2097152
#define W2O ((size_t)2097152)      // W2 bf16:  32*512*2     = 32768
#define AMO ((size_t)2129920)      // a_mem:    2048*32*2    = 131072
#define NMO ((size_t)2260992)      // n_mem:    2048*32*2    = 131072
#define HO  ((size_t)2392064)      // h bf16:   16384*512*2  = 16777216

__device__ __forceinline__ f32x4 mfma16(bf16x8 a, bf16x8 b, f32x4 c) {
    return __builtin_amdgcn_mfma_f32_16x16x32_bf16(a, b, c, 0, 0, 0);
}

__device__ __forceinline__ void gload_lds16(const void* g, void* l) {
    __builtin_amdgcn_global_load_lds(
        (const __attribute__((address_space(1))) void*)g,
        (__attribute__((address_space(3))) void*)l, 16, 0, 0);
}

__device__ __forceinline__ bf16x8 cvt8(f32x4 a, f32x4 b) {
    bf16x8 o;
    o[0] = (__bf16)a[0]; o[1] = (__bf16)a[1]; o[2] = (__bf16)a[2]; o[3] = (__bf16)a[3];
    o[4] = (__bf16)b[0]; o[5] = (__bf16)b[1]; o[6] = (__bf16)b[2]; o[7] = (__bf16)b[3];
    return o;
}

// ---------------- merged f32 -> bf16 conversion for W1, W2, am, nm ----------------
struct bf4 { __bf16 a, b, c, d; };

__global__ void cvt_all_kernel(const float* __restrict__ w1f, __bf16* __restrict__ w1b,
                               const float* __restrict__ w2f, __bf16* __restrict__ w2b,
                               const float* __restrict__ amf, __bf16* __restrict__ amb,
                               const float* __restrict__ nmf, __bf16* __restrict__ nmb) {
    const int g = blockIdx.x * blockDim.x + threadIdx.x;
    const int T = gridDim.x * blockDim.x;
    for (int i = g; i < (NH1 * DIM) / 4; i += T) {
        const float4 v = *reinterpret_cast<const float4*>(w1f + i * 4);
        *reinterpret_cast<bf4*>(w1b + i * 4) = { (__bf16)v.x, (__bf16)v.y, (__bf16)v.z, (__bf16)v.w };
    }
    for (int i = g; i < (NH2 * NH1) / 4; i += T) {
        const float4 v = *reinterpret_cast<const float4*>(w2f + i * 4);
        *reinterpret_cast<bf4*>(w2b + i * 4) = { (__bf16)v.x, (__bf16)v.y, (__bf16)v.z, (__bf16)v.w };
    }
    for (int i = g; i < (MMEM * NH2) / 4; i += T) {
        const float4 v = *reinterpret_cast<const float4*>(amf + i * 4);
        *reinterpret_cast<bf4*>(amb + i * 4) = { (__bf16)v.x, (__bf16)v.y, (__bf16)v.z, (__bf16)v.w };
    }
    for (int i = g; i < (MMEM * NH2) / 4; i += T) {
        const float4 v = *reinterpret_cast<const float4*>(nmf + i * 4);
        *reinterpret_cast<bf4*>(nmb + i * 4) = { (__bf16)v.x, (__bf16)v.y, (__bf16)v.z, (__bf16)v.w };
    }
}

// ---------------- GEMM1: h = relu(x @ W1^T + b1) ----------------
// 128x128 tile, BK=32, 4 waves (2x2, wave-tile 64x64). Tri-buffered LDS,
// BOTH operands staged via global_load_lds (A kept f32, cvt at fragment read).
// Pre-swizzled global sources (chunk ^= row) -> conflict-free ds_read_b128.
// One raw s_barrier + counted vmcnt per K-step; stage(t+2) issued after
// compute(t) => ~2 K-steps of latency cover; vmcnt never 0 until last tile.
__global__ __launch_bounds__(256, 2) void gemm1_kernel(
    const float*  __restrict__ Xf,  // [NROWS][DIM] f32
    const __bf16* __restrict__ W1,  // [NH1][DIM] bf16
    const float*  __restrict__ b1,  // [NH1]
    __bf16* __restrict__ Hout)      // [NROWS][NH1]
{
    __shared__ float  As[3][128 * BK];   // 16KB per buffer (f32)
    __shared__ __bf16 Bs[3][128 * BK];   // 8KB per buffer
    const int tid  = threadIdx.x;
    const int lane = tid & 63;
    const int wave = tid >> 6;
    // XCD swizzle: nwg=512 = 8*64. XCD c gets orig c*64..c*64+63 (16 row-panels x 4 cols)
    const int b = blockIdx.x;
    const int orig = (b & 7) * 64 + (b >> 3);
    const int bn = orig & 3;    // 4 col tiles of 128
    const int bm = orig >> 2;   // 128 row tiles of 128
    const size_t brow = (size_t)bm * 128;
    const int bcol = bn * 128;
    const int wr = wave >> 1, wc = wave & 1;

    f32x4 acc[4][4];
#pragma unroll
    for (int m = 0; m < 4; ++m)
#pragma unroll
        for (int n = 0; n < 4; ++n) acc[m][n] = (f32x4){0.f, 0.f, 0.f, 0.f};

    // ---- A staging: 4 gloads/thread. s_lin = q*256+tid; row = q*32 + (tid>>3);
    // stored slot = tid&7; source chunk = slot ^ (row&7) = (tid&7)^((tid>>3)&7).
    const int aRowT = tid >> 3;                       // 0..31
    const int cA    = (tid & 7) ^ (aRowT & 7);        // 16B-chunk within 128B row
    const float* aSrcBase = Xf + (brow + aRowT) * (size_t)DIM + cA * 4;
    // ---- B staging: 2 gloads/thread. row = q*64 + (tid>>2); slot = tid&3;
    // source chunk = (tid&3)^((tid>>2)&3).
    const int bRowT = tid >> 2;                       // 0..63
    const int cB    = (tid & 3) ^ (bRowT & 3);        // 16B-chunk within 64B row
    const __bf16* bSrcBase = W1 + (size_t)(bcol + bRowT) * DIM + cB * 8;

#define STAGE(T, BI)                                                          \
    {                                                                         \
        const int k0_ = (T) * BK;                                             \
        _Pragma("unroll")                                                     \
        for (int q = 0; q < 4; ++q)                                           \
            gload_lds16(aSrcBase + (size_t)q * 32 * DIM + k0_,                \
                        (char*)As[BI] + q * 4096 + tid * 16);                 \
        _Pragma("unroll")                                                     \
        for (int q = 0; q < 2; ++q)                                           \
            gload_lds16(bSrcBase + (size_t)q * 64 * DIM + k0_,                \
                        (char*)Bs[BI] + q * 4096 + tid * 16);                 \
    }

    // ---- fragment read geometry (swizzled slots are loop-invariant)
    const int l15 = lane & 15;
    const int kc  = lane >> 4;
    const int l7  = lane & 7;
    const int rABase = wr * 64 + l15;    // (row&7) == l7 for all m-frags
    const int rBBase = wc * 64 + l15;    // (row&3) == lane&3 for all n-frags
    const int aSlot0 = ((2 * kc)     ^ l7) << 4;
    const int aSlot1 = ((2 * kc + 1) ^ l7) << 4;
    const int bSlot  = (kc ^ (lane & 3)) << 4;

#define COMPUTE(BI)                                                           \
    {                                                                         \
        const char* Ac = (const char*)As[BI];                                 \
        const char* Bc = (const char*)Bs[BI];                                 \
        bf16x8 av[4], bv[4];                                                  \
        _Pragma("unroll")                                                     \
        for (int m = 0; m < 4; ++m) {                                         \
            const int rowB = (rABase + m * 16) * 128;                         \
            f32x4 lo = *(const f32x4*)(Ac + rowB + aSlot0);                   \
            f32x4 hi = *(const f32x4*)(Ac + rowB + aSlot1);                   \
            av[m] = cvt8(lo, hi);                                             \
        }                                                                     \
        _Pragma("unroll")                                                     \
        for (int n = 0; n < 4; ++n)                                           \
            bv[n] = *(const bf16x8*)(Bc + (rBBase + n * 16) * 64 + bSlot);    \
        __builtin_amdgcn_s_setprio(1);                                        \
        _Pragma("unroll")                                                     \
        for (int m = 0; m < 4; ++m)                                           \
            _Pragma("unroll")                                                 \
            for (int n = 0; n < 4; ++n)                                       \
                acc[m][n] = mfma16(av[m], bv[n], acc[m][n]);                  \
        __builtin_amdgcn_s_setprio(0);                                        \
    }

    // ================= prologue: stage tiles 0,1 (12 gloads in flight) ======
    STAGE(0, 0);
    STAGE(1, 1);

    // ================= main loop ===========================================
    // per iter: wait stage(t) [vmcnt(6): leaves stage(t+1)'s 6 in flight],
    // barrier, compute(t), issue stage(t+2). Buffer (t+2)%3 was last read at
    // compute(t-1), protected by this iteration's barrier.
    for (int t = 0; t < NT - 2; ++t) {
        const int bi = t % 3;
        asm volatile("s_waitcnt vmcnt(6)" ::: "memory");
        __builtin_amdgcn_s_barrier();
        __builtin_amdgcn_sched_barrier(0);
        COMPUTE(bi);
        __builtin_amdgcn_sched_barrier(0);
        const int bnx = (t + 2) % 3;
        STAGE(t + 2, bnx);
    }
    // tail: t = NT-2 (outstanding {NT-2, NT-1}), then t = NT-1
    {
        asm volatile("s_waitcnt vmcnt(6)" ::: "memory");
        __builtin_amdgcn_s_barrier();
        __builtin_amdgcn_sched_barrier(0);
        COMPUTE((NT - 2) % 3);
        asm volatile("s_waitcnt vmcnt(0)" ::: "memory");
        __builtin_amdgcn_s_barrier();
        __builtin_amdgcn_sched_barrier(0);
        COMPUTE((NT - 1) % 3);
    }
#undef STAGE
#undef COMPUTE

    // epilogue: bias + relu + bf16 store. D layout: col=lane&15, row=(lane>>4)*4+reg
#pragma unroll
    for (int n = 0; n < 4; ++n) {
        const int gcol = bcol + wc * 64 + n * 16 + l15;
        const float bias = b1[gcol];
#pragma unroll
        for (int m = 0; m < 4; ++m) {
            const size_t grow0 = brow + wr * 64 + m * 16 + kc * 4;
#pragma unroll
            for (int r = 0; r < 4; ++r) {
                float v = acc[m][n][r] + bias;
                v = v > 0.f ? v : 0.f;
                Hout[(grow0 + r) * NH1 + gcol] = (__bf16)v;
            }
        }
    }
}

// ---------------- Tail: feat = h@W2^T + b2; scores; sigmoid ----------------
__global__ __launch_bounds__(512) void tail_kernel(
    const __bf16* __restrict__ Hin,  // [NROWS][NH1]
    const __bf16* __restrict__ W2b,  // [NH2][NH1]
    const float*  __restrict__ b2,   // [NH2]
    const __bf16* __restrict__ Am,   // [MMEM][NH2]
    const __bf16* __restrict__ Nm,   // [MMEM][NH2]
    float* __restrict__ out)         // [NROWS]
{
    __shared__ __bf16 featLds[64 * 32];
    __shared__ float aMaxLds[2][64];
    __shared__ float nMaxLds[2][64];
    const int tid  = threadIdx.x;
    const int lane = tid & 63;
    const int wave = tid >> 6;          // 0..7
    const int rowBase = blockIdx.x * 64;
    const int l15 = lane & 15;
    const int kc  = lane >> 4;
    const int rgrp  = (wave & 3) * 16;
    const int jHalf = wave >> 2;

    if (wave < 4) {
        f32x4 acc0 = {0.f,0.f,0.f,0.f}, acc1 = {0.f,0.f,0.f,0.f};
        const size_t hrow = (size_t)(rowBase + rgrp + l15) * NH1;
#pragma unroll
        for (int kk = 0; kk < 16; ++kk) {
            bf16x8 a  = *(const bf16x8*)(Hin + hrow + kk * 32 + kc * 8);
            bf16x8 w0 = *(const bf16x8*)(W2b + (size_t)l15 * NH1 + kk * 32 + kc * 8);
            bf16x8 w1 = *(const bf16x8*)(W2b + (size_t)(16 + l15) * NH1 + kk * 32 + kc * 8);
            acc0 = mfma16(a, w0, acc0);
            acc1 = mfma16(a, w1, acc1);
        }
        const float bias0 = b2[l15], bias1 = b2[16 + l15];
#pragma unroll
        for (int r = 0; r < 4; ++r) {
            const int lr = rgrp + kc * 4 + r;
            featLds[lr * 32 + l15]      = (__bf16)(acc0[r] + bias0);
            featLds[lr * 32 + 16 + l15] = (__bf16)(acc1[r] + bias1);
        }
    }
    __syncthreads();

    const bf16x8 af = *(const bf16x8*)&featLds[(rgrp + l15) * 32 + kc * 8];

    float rmaxA[4], rmaxN[4];
#pragma unroll
    for (int r = 0; r < 4; ++r) { rmaxA[r] = -1e30f; rmaxN[r] = -1e30f; }
    const f32x4 zero = {0.f,0.f,0.f,0.f};
    const int jBase = jHalf * (MMEM / 2);
#pragma unroll 2
    for (int jt = 0; jt < (MMEM / 2) / 16; jt += 4) {
        bf16x8 ba[4], bb[4];
#pragma unroll
        for (int u = 0; u < 4; ++u) {
            const size_t off = (size_t)(jBase + (jt + u) * 16 + l15) * NH2 + kc * 8;
            ba[u] = *(const bf16x8*)(Am + off);
            bb[u] = *(const bf16x8*)(Nm + off);
        }
#pragma unroll
        for (int u = 0; u < 4; ++u) {
            f32x4 sa = mfma16(af, ba[u], zero);
            f32x4 sn = mfma16(af, bb[u], zero);
#pragma unroll
            for (int r = 0; r < 4; ++r) {
                rmaxA[r] = fmaxf(rmaxA[r], sa[r]);
                rmaxN[r] = fmaxf(rmaxN[r], sn[r]);
            }
        }
    }
#pragma unroll
    for (int off = 1; off < 16; off <<= 1) {
#pragma unroll
        for (int r = 0; r < 4; ++r) {
            rmaxA[r] = fmaxf(rmaxA[r], __shfl_xor(rmaxA[r], off, 64));
            rmaxN[r] = fmaxf(rmaxN[r], __shfl_xor(rmaxN[r], off, 64));
        }
    }
    if (l15 == 0) {
#pragma unroll
        for (int r = 0; r < 4; ++r) {
            const int row = rgrp + kc * 4 + r;
            aMaxLds[jHalf][row] = rmaxA[r];
            nMaxLds[jHalf][row] = rmaxN[r];
        }
    }
    __syncthreads();
    if (tid < 64) {
        const float ma = fmaxf(aMaxLds[0][tid], aMaxLds[1][tid]);
        const float mn = fmaxf(nMaxLds[0][tid], nMaxLds[1][tid]);
        const float d = (ma - mn) * (1.0f / 32.0f);
        out[rowBase + tid] = 1.0f / (1.0f + __expf(-d));
    }
}

extern "C" void kernel_launch(void* const* d_in, const int* in_sizes, int n_in,
                              void* d_out, int out_size, void* d_ws, size_t ws_size,
                              hipStream_t stream) {
    (void)in_sizes; (void)n_in; (void)out_size; (void)ws_size;
    const float* x  = (const float*)d_in[0];
    const float* W1 = (const float*)d_in[1];
    const float* b1 = (const float*)d_in[2];
    const float* W2 = (const float*)d_in[3];
    const float* b2 = (const float*)d_in[4];
    const float* am = (const float*)d_in[5];
    const float* nm = (const float*)d_in[6];
    float* out = (float*)d_out;
    char* ws = (char*)d_ws;
    __bf16* w1b = (__bf16*)(ws + W1O);
    __bf16* w2b = (__bf16*)(ws + W2O);
    __bf16* amb = (__bf16*)(ws + AMO);
    __bf16* nmb = (__bf16*)(ws + NMO);
    __bf16* hb  = (__bf16*)(ws + HO);

    cvt_all_kernel<<<dim3(512), dim3(256), 0, stream>>>(W1, w1b, W2, w2b, am, amb, nm, nmb);
    gemm1_kernel<<<dim3((NROWS / 128) * (NH1 / 128)), dim3(256), 0, stream>>>(x, w1b, b1, hb);
    tail_kernel<<<dim3(NROWS / 64), dim3(512), 0, stream>>>(hb, w2b, b2, amb, nmb, out);
}